// Round 1
// baseline (399.779 us; speedup 1.0000x reference)
//
#include <hip/hip_runtime.h>
#include <math.h>

#define N 8000
#define D 256
#define P 128
#define NQ 2000   // float4 per adj row
#define MW 128    // mask words (ull) per row: 4 planes x 32 words

// Mask layout (built from wave ballots, fully-coalesced adj reads):
//   plane c (c=0..3 = float4 component), word q (0..31), bit l (0..63)
//   <=> adj column (q*64 + l)*4 + c.  Row stride = 128 ull = 1 KB.

__device__ __forceinline__ unsigned int spread4(unsigned int b) {
    // 8 bits -> bits at positions 0,4,8,...,28
    b = (b | (b << 12)) & 0x000F000Fu;
    b = (b | (b << 6))  & 0x03030303u;
    b = (b | (b << 3))  & 0x11111111u;
    return b;
}

// ---------------------------------------------------------------------------
// K1 (fused): blocks [0,P): projection for positive p = blockIdx:
//               projT[d][p] = b_att[d] + sum_k emb[pos[p]][k]*w_att[d][k]
//               pe2[p]      = sum_d emb[pos[p]][d]*w_weight[D+d]
//             blocks [P, P+N): row r = blockIdx-P:
//               dinv[r] = rsqrt(rowsum(adj)), bitmask planes via __ballot.
// adj reads are lane-stride-16B coalesced: idx = k*256 + tid.
// ---------------------------------------------------------------------------
__global__ __launch_bounds__(256) void prep_kernel(const float* __restrict__ adj,
                                                   const float* __restrict__ emb,
                                                   const float* __restrict__ w_att,
                                                   const float* __restrict__ b_att,
                                                   const float* __restrict__ w_weight,
                                                   const int* __restrict__ pos_idx,
                                                   float* __restrict__ dinv,
                                                   unsigned long long* __restrict__ msk,
                                                   float* __restrict__ projT,
                                                   float* __restrict__ pe2) {
    int tid = threadIdx.x;
    if (blockIdx.x >= P) {
        // ---- degree + bitmask path (coalesced) ----
        int row = blockIdx.x - P;
        const float4* r = (const float4*)(adj + (size_t)row * N);
        unsigned long long* mrow = msk + (size_t)row * MW;
        int lane = tid & 63, wave = tid >> 6;
        float s = 0.f;
        #pragma unroll
        for (int k = 0; k < 8; k++) {
            int idx = k * 256 + tid;                  // lane-stride 16B: coalesced
            float4 a = make_float4(0.f, 0.f, 0.f, 0.f);
            if (idx < NQ) a = r[idx];
            s += a.x + a.y + a.z + a.w;
            unsigned long long bx = __ballot(a.x != 0.f);
            unsigned long long by = __ballot(a.y != 0.f);
            unsigned long long bz = __ballot(a.z != 0.f);
            unsigned long long bw = __ballot(a.w != 0.f);
            if (lane == 0) {
                int q = k * 4 + wave;                 // ull word index within plane
                mrow[q]      = bx;
                mrow[32 + q] = by;
                mrow[64 + q] = bz;
                mrow[96 + q] = bw;
            }
        }
        for (int off = 32; off > 0; off >>= 1) s += __shfl_down(s, off, 64);
        __shared__ float red4[4];
        if (lane == 0) red4[wave] = s;
        __syncthreads();
        if (tid == 0) dinv[row] = rsqrtf(red4[0] + red4[1] + red4[2] + red4[3]);
    } else {
        // ---- projection path (runs first, hides under the degree flood) ----
        int p = blockIdx.x;
        int row = pos_idx[p];
        __shared__ float e[D];
        __shared__ float red[D];
        e[tid] = emb[(size_t)row * D + tid];
        __syncthreads();
        float acc = b_att[tid];
        const float* wrow = w_att + (size_t)tid * D;
        #pragma unroll 4
        for (int k = 0; k < D; k++) acc += e[k] * wrow[k];
        projT[(size_t)tid * P + p] = acc;
        red[tid] = e[tid] * w_weight[D + tid];
        __syncthreads();
        for (int s = 128; s > 0; s >>= 1) {
            if (tid < s) red[tid] += red[tid + s];
            __syncthreads();
        }
        if (tid == 0) pe2[p] = red[0];
    }
}

// ---------------------------------------------------------------------------
// K2: fused scores GEMM + bitmask mask + column softmax + mutual_w + hop 1.
// 250 blocks x 256 threads; block owns 32 nodes x all 128 positives.
// Thread (tx,ty) = (tid&7, tid>>3) owns 4n x 4p; K chunks of 32.
// Per-p 32-bit stripe word reassembled from the 4 bitplanes.
// ---------------------------------------------------------------------------
__global__ __launch_bounds__(256) void attn_kernel(const float* __restrict__ emb,
                                                   const float* __restrict__ projT,
                                                   const unsigned long long* __restrict__ msk,
                                                   const int* __restrict__ pos_idx,
                                                   const float* __restrict__ pe2,
                                                   const float* __restrict__ w_weight,
                                                   const float* __restrict__ dinv,
                                                   float* __restrict__ v) {
    __shared__ float At[32][36];        // At[dk][nn] = emb[n0+nn][d0+dk], +4 pad
    __shared__ float B[32][128];        // B[dk][p]   = projT[d0+dk][p]
    __shared__ float S[32][129];        // masked scores, padded
    __shared__ unsigned int mword[P];   // 32-col stripe mask word per p
    __shared__ int   posrow[P];
    __shared__ float pe2s[P];
    __shared__ float fac[P];            // deduped dinv[pos[p]]
    __shared__ float w1[D];

    int tid = threadIdx.x;
    int tx = tid & 7;     // n-group: n = n0 + tx*4 + i
    int ty = tid >> 3;    // p-group: p = ty*4 + j
    int n0 = blockIdx.x * 32;

    if (tid < P) {
        int r0 = pos_idx[tid];
        posrow[tid] = r0;
        pe2s[tid] = pe2[tid];
        float f = dinv[r0];
        if (tid > 0 && pos_idx[tid - 1] == r0) f = 0.f;  // dedupe (sorted idx)
        fac[tid] = f;
    }
    w1[tid] = w_weight[tid];

    float acc[4][4];
    #pragma unroll
    for (int i = 0; i < 4; i++)
        #pragma unroll
        for (int j = 0; j < 4; j++) acc[i][j] = 0.f;
    float e1 = 0.f;   // emb[n].w1 for n = n0 + tid (threads tid<32)

    for (int d0 = 0; d0 < D; d0 += 32) {
        __syncthreads();   // covers init stores on first iter, tile reuse after
        {   // stage A chunk transposed: 1024 floats, 4 per thread
            int nn = tid >> 3;
            int dk0 = (tid & 7) * 4;
            float4 v0 = *(const float4*)(emb + (size_t)(n0 + nn) * D + d0 + dk0);
            At[dk0 + 0][nn] = v0.x; At[dk0 + 1][nn] = v0.y;
            At[dk0 + 2][nn] = v0.z; At[dk0 + 3][nn] = v0.w;
        }
        #pragma unroll
        for (int r = 0; r < 4; r++) {   // stage B chunk: 4096 floats
            int f = (r * 256 + tid) * 4;
            int dk = f >> 7, pp = f & 127;
            *(float4*)&B[dk][pp] = *(const float4*)(projT + (size_t)(d0 + dk) * P + pp);
        }
        __syncthreads();
        #pragma unroll
        for (int dk = 0; dk < 32; dk++) {
            float4 a4 = *(const float4*)&At[dk][tx * 4];
            float4 b4 = *(const float4*)&B[dk][ty * 4];
            acc[0][0] += a4.x * b4.x; acc[0][1] += a4.x * b4.y;
            acc[0][2] += a4.x * b4.z; acc[0][3] += a4.x * b4.w;
            acc[1][0] += a4.y * b4.x; acc[1][1] += a4.y * b4.y;
            acc[1][2] += a4.y * b4.z; acc[1][3] += a4.y * b4.w;
            acc[2][0] += a4.z * b4.x; acc[2][1] += a4.z * b4.y;
            acc[2][2] += a4.z * b4.z; acc[2][3] += a4.z * b4.w;
            acc[3][0] += a4.w * b4.x; acc[3][1] += a4.w * b4.y;
            acc[3][2] += a4.w * b4.z; acc[3][3] += a4.w * b4.w;
        }
        if (tid < 32) {  // fold e1 = emb[n].w1 using the staged tile
            float t = 0.f;
            #pragma unroll
            for (int dk = 0; dk < 32; dk++) t += At[dk][tid] * w1[d0 + dk];
            e1 += t;
        }
    }

    // reassemble the 32-column stripe word from 4 bitplanes:
    // bit nn (= 4i+c) of mword[p] = bit i of byte (plane c >> sh)
    if (tid < P) {
        size_t base = (size_t)posrow[tid] * MW;
        int q  = n0 >> 8;               // plane word index
        int sh = (n0 >> 2) & 63;        // bit offset of this stripe's 8 float4
        unsigned int b0 = (unsigned int)((msk[base +      q] >> sh) & 0xFFu);
        unsigned int b1 = (unsigned int)((msk[base + 32 + q] >> sh) & 0xFFu);
        unsigned int b2 = (unsigned int)((msk[base + 64 + q] >> sh) & 0xFFu);
        unsigned int b3 = (unsigned int)((msk[base + 96 + q] >> sh) & 0xFFu);
        mword[tid] = spread4(b0) | (spread4(b1) << 1) | (spread4(b2) << 2) | (spread4(b3) << 3);
    }
    __syncthreads();

    // mask + write scores
    #pragma unroll
    for (int j = 0; j < 4; j++) {
        int p = ty * 4 + j;
        unsigned int w = mword[p];
        #pragma unroll
        for (int i = 0; i < 4; i++) {
            int nn = tx * 4 + i;
            S[nn][p] = ((w >> nn) & 1u) ? acc[i][j] : 0.f;
        }
    }
    __syncthreads();

    // softmax over p + context-fold + hop-1 + sigmoid + v write
    if (tid < 32) {
        int n = n0 + tid;
        float mm = -1e30f;
        for (int p = 0; p < P; p++) mm = fmaxf(mm, S[tid][p]);
        float Z = 0.f, ape = 0.f, vs = 0.f;
        for (int p = 0; p < P; p++) {
            float ex = __expf(S[tid][p] - mm);
            Z += ex;
            ape += ex * pe2s[p];
            if ((mword[p] >> tid) & 1u) vs += fac[p];
        }
        float logit = e1 + ape / Z;
        float mw = 1.f / (1.f + __expf(-logit));
        v[n] = vs * dinv[n] * mw;
    }
}

// ---------------------------------------------------------------------------
// K3: out[j] = w_final * dinv[j] * sum_{n: bit(j,n)} v[n]   (adj symmetric)
// One wave per row (4 rows/block); iterate set bits of the 4 bitplanes.
// word wi: plane c = wi>>5, q = wi&31; bit k -> column q*256 + 4k + c.
// ---------------------------------------------------------------------------
__global__ __launch_bounds__(256) void final_kernel(const unsigned long long* __restrict__ msk,
                                                    const float* __restrict__ vvec,
                                                    const float* __restrict__ dinv,
                                                    const float* __restrict__ w_final,
                                                    float* __restrict__ out) {
    int wave = threadIdx.x >> 6, lane = threadIdx.x & 63;
    int row = blockIdx.x * 4 + wave;
    const unsigned long long* mrow = msk + (size_t)row * MW;
    float s = 0.f;
    #pragma unroll
    for (int t = 0; t < 2; t++) {
        int wi = t * 64 + lane;
        unsigned long long m = mrow[wi];
        int c = wi >> 5;
        int q = wi & 31;
        int base = q * 256 + c;
        while (m) {
            int k = __builtin_ctzll(m);
            s += vvec[base + 4 * k];
            m &= m - 1;
        }
    }
    for (int off = 32; off > 0; off >>= 1) s += __shfl_down(s, off, 64);
    if (lane == 0) out[row] = s * dinv[row] * w_final[0];
}

// ---------------------------------------------------------------------------
extern "C" void kernel_launch(void* const* d_in, const int* in_sizes, int n_in,
                              void* d_out, int out_size, void* d_ws, size_t ws_size,
                              hipStream_t stream) {
    const float* adj    = (const float*)d_in[0];
    const float* emb    = (const float*)d_in[1];
    const float* w_att  = (const float*)d_in[2];
    const float* b_att  = (const float*)d_in[3];
    const float* w_w    = (const float*)d_in[4];
    const float* w_f    = (const float*)d_in[5];
    const int*   pos    = (const int*)d_in[6];
    float* out = (float*)d_out;

    float* ws     = (float*)d_ws;
    float* dinv   = ws;                       // N
    float* projT  = dinv + N;                 // D*P
    float* pe2    = projT + (size_t)D * P;    // P
    float* v      = pe2 + P;                  // N
    // byte offset of msk = (N + D*P + P + N)*4 = 195584, 8B-aligned
    unsigned long long* msk = (unsigned long long*)(v + N);  // 8000*128 ull = 8.19 MB

    prep_kernel <<<N + P,  256, 0, stream>>>(adj, emb, w_att, b_att, w_w, pos,
                                             dinv, msk, projT, pe2);
    attn_kernel <<<N / 32, 256, 0, stream>>>(emb, projT, msk, pos, pe2, w_w, dinv, v);
    final_kernel<<<N / 4,  256, 0, stream>>>(msk, v, dinv, w_f, out);
}

// Round 2
// 375.800 us; speedup vs baseline: 1.0638x; 1.0638x over previous
//
#include <hip/hip_runtime.h>
#include <math.h>

#define N 8000
#define D 256
#define P 128
#define NQ 2000   // float4 per adj row
#define MW 128    // mask words (ull) per row: 4 planes x 32 words

typedef float f4v __attribute__((ext_vector_type(4)));

// Mask layout (built from wave ballots, fully-coalesced adj reads):
//   plane c (c=0..3 = float4 component), word q (0..31), bit l (0..63)
//   <=> adj column (q*64 + l)*4 + c.  Row stride = 128 ull = 1 KB.

__device__ __forceinline__ unsigned int spread4(unsigned int b) {
    // 8 bits -> bits at positions 0,4,8,...,28
    b = (b | (b << 12)) & 0x000F000Fu;
    b = (b | (b << 6))  & 0x03030303u;
    b = (b | (b << 3))  & 0x11111111u;
    return b;
}

// ---------------------------------------------------------------------------
// K1 (fused): blocks [0,P): projection for positive p = blockIdx:
//               projT[d][p] = b_att[d] + sum_k emb[pos[p]][k]*w_att[d][k]
//               pe2[p]      = sum_d emb[pos[p]][d]*w_weight[D+d]
//             blocks [P, P+N): row r = blockIdx-P:
//               dinv[r] = rsqrt(rowsum(adj)), bitmask planes via __ballot.
// adj reads are lane-stride-16B coalesced + nontemporal (streamed once).
// msk row staged in LDS, stored as one coalesced 1KB write.
// ---------------------------------------------------------------------------
__global__ __launch_bounds__(256) void prep_kernel(const float* __restrict__ adj,
                                                   const float* __restrict__ emb,
                                                   const float* __restrict__ w_att,
                                                   const float* __restrict__ b_att,
                                                   const float* __restrict__ w_weight,
                                                   const int* __restrict__ pos_idx,
                                                   float* __restrict__ dinv,
                                                   unsigned long long* __restrict__ msk,
                                                   float* __restrict__ projT,
                                                   float* __restrict__ pe2) {
    int tid = threadIdx.x;
    if (blockIdx.x >= P) {
        // ---- degree + bitmask path (coalesced, streaming) ----
        int row = blockIdx.x - P;
        const f4v* r = (const f4v*)(adj + (size_t)row * N);
        unsigned long long* mrow = msk + (size_t)row * MW;
        __shared__ unsigned long long mbuf[MW];
        __shared__ float red4[4];
        int lane = tid & 63, wave = tid >> 6;
        float s = 0.f;
        #pragma unroll
        for (int k = 0; k < 8; k++) {
            int idx = k * 256 + tid;                  // lane-stride 16B: coalesced
            f4v a = {0.f, 0.f, 0.f, 0.f};
            if (idx < NQ) a = __builtin_nontemporal_load(r + idx);
            s += a.x + a.y + a.z + a.w;
            unsigned long long bx = __ballot(a.x != 0.f);
            unsigned long long by = __ballot(a.y != 0.f);
            unsigned long long bz = __ballot(a.z != 0.f);
            unsigned long long bw = __ballot(a.w != 0.f);
            if (lane == 0) {
                int q = k * 4 + wave;                 // ull word index within plane
                mbuf[q]      = bx;
                mbuf[32 + q] = by;
                mbuf[64 + q] = bz;
                mbuf[96 + q] = bw;
            }
        }
        for (int off = 32; off > 0; off >>= 1) s += __shfl_down(s, off, 64);
        if (lane == 0) red4[wave] = s;
        __syncthreads();
        if (tid < MW) mrow[tid] = mbuf[tid];          // coalesced 1KB store
        if (tid == 0) dinv[row] = rsqrtf(red4[0] + red4[1] + red4[2] + red4[3]);
    } else {
        // ---- projection path (runs first, hides under the degree flood) ----
        int p = blockIdx.x;
        int row = pos_idx[p];
        __shared__ float e[D];
        __shared__ float red[D];
        e[tid] = emb[(size_t)row * D + tid];
        __syncthreads();
        float acc = b_att[tid];
        const float* wrow = w_att + (size_t)tid * D;
        #pragma unroll 4
        for (int k = 0; k < D; k++) acc += e[k] * wrow[k];
        projT[(size_t)tid * P + p] = acc;
        red[tid] = e[tid] * w_weight[D + tid];
        __syncthreads();
        for (int s = 128; s > 0; s >>= 1) {
            if (tid < s) red[tid] += red[tid + s];
            __syncthreads();
        }
        if (tid == 0) pe2[p] = red[0];
    }
}

// ---------------------------------------------------------------------------
// K2: fused scores GEMM + bitmask mask + column softmax + mutual_w + hop 1.
// 250 blocks x 512 threads (8 waves = 2/SIMD for latency hiding);
// block owns 32 nodes x all 128 positives.
// Thread (tx,ty) = (tid&15, tid>>4) owns 2n x 4p; K chunks of 32.
// Per-p 32-bit stripe word reassembled from the 4 bitplanes.
// ---------------------------------------------------------------------------
__global__ __launch_bounds__(512) void attn_kernel(const float* __restrict__ emb,
                                                   const float* __restrict__ projT,
                                                   const unsigned long long* __restrict__ msk,
                                                   const int* __restrict__ pos_idx,
                                                   const float* __restrict__ pe2,
                                                   const float* __restrict__ w_weight,
                                                   const float* __restrict__ dinv,
                                                   float* __restrict__ v) {
    __shared__ float At[32][36];        // At[dk][nn] = emb[n0+nn][d0+dk], +4 pad
    __shared__ float B[32][128];        // B[dk][p]   = projT[d0+dk][p]
    __shared__ float S[32][129];        // masked scores, padded
    __shared__ unsigned int mword[P];   // 32-col stripe mask word per p
    __shared__ int   posrow[P];
    __shared__ float pe2s[P];
    __shared__ float fac[P];            // deduped dinv[pos[p]]
    __shared__ float w1[D];

    int tid = threadIdx.x;
    int tx = tid & 15;    // n-group: n = n0 + tx*2 + i
    int ty = tid >> 4;    // p-group: p = ty*4 + j
    int n0 = blockIdx.x * 32;

    if (tid < P) {
        int r0 = pos_idx[tid];
        posrow[tid] = r0;
        pe2s[tid] = pe2[tid];
        float f = dinv[r0];
        if (tid > 0 && pos_idx[tid - 1] == r0) f = 0.f;  // dedupe (sorted idx)
        fac[tid] = f;
    }
    if (tid < D) w1[tid] = w_weight[tid];

    float acc[2][4];
    #pragma unroll
    for (int i = 0; i < 2; i++)
        #pragma unroll
        for (int j = 0; j < 4; j++) acc[i][j] = 0.f;
    float e1 = 0.f;   // emb[n].w1 for n = n0 + tid (threads tid<32)

    for (int d0 = 0; d0 < D; d0 += 32) {
        __syncthreads();   // covers init stores on first iter, tile reuse after
        if (tid < 256) {   // stage A chunk transposed: 1024 floats
            int nn = tid >> 3;
            int dk0 = (tid & 7) * 4;
            float4 v0 = *(const float4*)(emb + (size_t)(n0 + nn) * D + d0 + dk0);
            At[dk0 + 0][nn] = v0.x; At[dk0 + 1][nn] = v0.y;
            At[dk0 + 2][nn] = v0.z; At[dk0 + 3][nn] = v0.w;
        }
        #pragma unroll
        for (int r = 0; r < 2; r++) {   // stage B chunk: 4096 floats
            int f = (r * 512 + tid) * 4;
            int dk = f >> 7, pp = f & 127;
            *(float4*)&B[dk][pp] = *(const float4*)(projT + (size_t)(d0 + dk) * P + pp);
        }
        __syncthreads();
        #pragma unroll
        for (int dk = 0; dk < 32; dk++) {
            float a0 = At[dk][tx * 2 + 0];
            float a1 = At[dk][tx * 2 + 1];
            float4 b4 = *(const float4*)&B[dk][ty * 4];
            acc[0][0] += a0 * b4.x; acc[0][1] += a0 * b4.y;
            acc[0][2] += a0 * b4.z; acc[0][3] += a0 * b4.w;
            acc[1][0] += a1 * b4.x; acc[1][1] += a1 * b4.y;
            acc[1][2] += a1 * b4.z; acc[1][3] += a1 * b4.w;
        }
        if (tid < 32) {  // fold e1 = emb[n].w1 using the staged tile
            float t = 0.f;
            #pragma unroll
            for (int dk = 0; dk < 32; dk++) t += At[dk][tid] * w1[d0 + dk];
            e1 += t;
        }
    }

    // reassemble the 32-column stripe word from 4 bitplanes:
    // bit nn (= 4i+c) of mword[p] = bit i of byte (plane c >> sh)
    if (tid < P) {
        size_t base = (size_t)posrow[tid] * MW;
        int q  = n0 >> 8;               // plane word index
        int sh = (n0 >> 2) & 63;        // bit offset of this stripe's 8 float4
        unsigned int b0 = (unsigned int)((msk[base +      q] >> sh) & 0xFFu);
        unsigned int b1 = (unsigned int)((msk[base + 32 + q] >> sh) & 0xFFu);
        unsigned int b2 = (unsigned int)((msk[base + 64 + q] >> sh) & 0xFFu);
        unsigned int b3 = (unsigned int)((msk[base + 96 + q] >> sh) & 0xFFu);
        mword[tid] = spread4(b0) | (spread4(b1) << 1) | (spread4(b2) << 2) | (spread4(b3) << 3);
    }
    __syncthreads();

    // mask + write scores
    #pragma unroll
    for (int j = 0; j < 4; j++) {
        int p = ty * 4 + j;
        unsigned int w = mword[p];
        #pragma unroll
        for (int i = 0; i < 2; i++) {
            int nn = tx * 2 + i;
            S[nn][p] = ((w >> nn) & 1u) ? acc[i][j] : 0.f;
        }
    }
    __syncthreads();

    // softmax over p + context-fold + hop-1 + sigmoid + v write
    if (tid < 32) {
        int n = n0 + tid;
        float mm = -1e30f;
        for (int p = 0; p < P; p++) mm = fmaxf(mm, S[tid][p]);
        float Z = 0.f, ape = 0.f, vs = 0.f;
        for (int p = 0; p < P; p++) {
            float ex = __expf(S[tid][p] - mm);
            Z += ex;
            ape += ex * pe2s[p];
            if ((mword[p] >> tid) & 1u) vs += fac[p];
        }
        float logit = e1 + ape / Z;
        float mw = 1.f / (1.f + __expf(-logit));
        v[n] = vs * dinv[n] * mw;
    }
}

// ---------------------------------------------------------------------------
// K3: out[j] = w_final * dinv[j] * sum_{n: bit(j,n)} v[n]   (adj symmetric)
// One wave per row (4 rows/block); iterate set bits of the 4 bitplanes.
// word wi: plane c = wi>>5, q = wi&31; bit k -> column q*256 + 4k + c.
// ---------------------------------------------------------------------------
__global__ __launch_bounds__(256) void final_kernel(const unsigned long long* __restrict__ msk,
                                                    const float* __restrict__ vvec,
                                                    const float* __restrict__ dinv,
                                                    const float* __restrict__ w_final,
                                                    float* __restrict__ out) {
    int wave = threadIdx.x >> 6, lane = threadIdx.x & 63;
    int row = blockIdx.x * 4 + wave;
    const unsigned long long* mrow = msk + (size_t)row * MW;
    float s = 0.f;
    #pragma unroll
    for (int t = 0; t < 2; t++) {
        int wi = t * 64 + lane;
        unsigned long long m = mrow[wi];
        int c = wi >> 5;
        int q = wi & 31;
        int base = q * 256 + c;
        while (m) {
            int k = __builtin_ctzll(m);
            s += vvec[base + 4 * k];
            m &= m - 1;
        }
    }
    for (int off = 32; off > 0; off >>= 1) s += __shfl_down(s, off, 64);
    if (lane == 0) out[row] = s * dinv[row] * w_final[0];
}

// ---------------------------------------------------------------------------
extern "C" void kernel_launch(void* const* d_in, const int* in_sizes, int n_in,
                              void* d_out, int out_size, void* d_ws, size_t ws_size,
                              hipStream_t stream) {
    const float* adj    = (const float*)d_in[0];
    const float* emb    = (const float*)d_in[1];
    const float* w_att  = (const float*)d_in[2];
    const float* b_att  = (const float*)d_in[3];
    const float* w_w    = (const float*)d_in[4];
    const float* w_f    = (const float*)d_in[5];
    const int*   pos    = (const int*)d_in[6];
    float* out = (float*)d_out;

    float* ws     = (float*)d_ws;
    float* dinv   = ws;                       // N
    float* projT  = dinv + N;                 // D*P
    float* pe2    = projT + (size_t)D * P;    // P
    float* v      = pe2 + P;                  // N
    // byte offset of msk = (N + D*P + P + N)*4 = 195584, 8B-aligned
    unsigned long long* msk = (unsigned long long*)(v + N);  // 8000*128 ull = 8.19 MB

    prep_kernel <<<N + P,  256, 0, stream>>>(adj, emb, w_att, b_att, w_w, pos,
                                             dinv, msk, projT, pe2);
    attn_kernel <<<N / 32, 512, 0, stream>>>(emb, projT, msk, pos, pe2, w_w, dinv, v);
    final_kernel<<<N / 4,  256, 0, stream>>>(msk, v, dinv, w_f, out);
}

// Round 3
// 365.026 us; speedup vs baseline: 1.0952x; 1.0295x over previous
//
#include <hip/hip_runtime.h>
#include <math.h>

#define N 8000
#define D 256
#define P 128
#define NQ 2000   // float4 per adj row
#define MW 128    // mask words (ull) per row: 4 planes x 32 words

typedef float f4v __attribute__((ext_vector_type(4)));

// Mask layout (built from wave ballots, fully-coalesced adj reads):
//   plane c (c=0..3 = float4 component), word q (0..31), bit l (0..63)
//   <=> adj column (q*64 + l)*4 + c.  Row stride = 128 ull = 1 KB.

__device__ __forceinline__ unsigned int spread4(unsigned int b) {
    // 8 bits -> bits at positions 0,4,8,...,28
    b = (b | (b << 12)) & 0x000F000Fu;
    b = (b | (b << 6))  & 0x03030303u;
    b = (b | (b << 3))  & 0x11111111u;
    return b;
}

// ---------------------------------------------------------------------------
// K1 (fused): blocks [0,P): projection for positive p = blockIdx:
//               projT[d][p] = b_att[d] + sum_k emb[pos[p]][k]*w_att[d][k]
//               pe2[p]      = sum_d emb[pos[p]][d]*w_weight[D+d]
//             blocks [P, P+N): row r = blockIdx-P:
//               dinv[r] = rsqrt(rowsum(adj)), bitmask planes via __ballot.
// adj reads are lane-stride-16B coalesced + nontemporal (streamed once).
// msk row staged in LDS, stored as one coalesced 1KB write.
// ---------------------------------------------------------------------------
__global__ __launch_bounds__(256) void prep_kernel(const float* __restrict__ adj,
                                                   const float* __restrict__ emb,
                                                   const float* __restrict__ w_att,
                                                   const float* __restrict__ b_att,
                                                   const float* __restrict__ w_weight,
                                                   const int* __restrict__ pos_idx,
                                                   float* __restrict__ dinv,
                                                   unsigned long long* __restrict__ msk,
                                                   float* __restrict__ projT,
                                                   float* __restrict__ pe2) {
    int tid = threadIdx.x;
    if (blockIdx.x >= P) {
        // ---- degree + bitmask path (coalesced, streaming) ----
        int row = blockIdx.x - P;
        const f4v* r = (const f4v*)(adj + (size_t)row * N);
        unsigned long long* mrow = msk + (size_t)row * MW;
        __shared__ unsigned long long mbuf[MW];
        __shared__ float red4[4];
        int lane = tid & 63, wave = tid >> 6;
        float s = 0.f;
        #pragma unroll
        for (int k = 0; k < 8; k++) {
            int idx = k * 256 + tid;                  // lane-stride 16B: coalesced
            f4v a = {0.f, 0.f, 0.f, 0.f};
            if (idx < NQ) a = __builtin_nontemporal_load(r + idx);
            s += a.x + a.y + a.z + a.w;
            unsigned long long bx = __ballot(a.x != 0.f);
            unsigned long long by = __ballot(a.y != 0.f);
            unsigned long long bz = __ballot(a.z != 0.f);
            unsigned long long bw = __ballot(a.w != 0.f);
            if (lane == 0) {
                int q = k * 4 + wave;                 // ull word index within plane
                mbuf[q]      = bx;
                mbuf[32 + q] = by;
                mbuf[64 + q] = bz;
                mbuf[96 + q] = bw;
            }
        }
        for (int off = 32; off > 0; off >>= 1) s += __shfl_down(s, off, 64);
        if (lane == 0) red4[wave] = s;
        __syncthreads();
        if (tid < MW) mrow[tid] = mbuf[tid];          // coalesced 1KB store
        if (tid == 0) dinv[row] = rsqrtf(red4[0] + red4[1] + red4[2] + red4[3]);
    } else {
        // ---- projection path (runs first, hides under the degree flood) ----
        int p = blockIdx.x;
        int row = pos_idx[p];
        __shared__ float e[D];
        __shared__ float red[D];
        e[tid] = emb[(size_t)row * D + tid];
        __syncthreads();
        float acc = b_att[tid];
        const float* wrow = w_att + (size_t)tid * D;
        #pragma unroll 4
        for (int k = 0; k < D; k++) acc += e[k] * wrow[k];
        projT[(size_t)tid * P + p] = acc;
        red[tid] = e[tid] * w_weight[D + tid];
        __syncthreads();
        for (int s = 128; s > 0; s >>= 1) {
            if (tid < s) red[tid] += red[tid + s];
            __syncthreads();
        }
        if (tid == 0) pe2[p] = red[0];
    }
}

// ---------------------------------------------------------------------------
// K2: fused scores GEMM + bitmask mask + column softmax + mutual_w + hop 1.
// 250 blocks x 512 threads (8 waves = 2/SIMD); block owns 32 nodes x 128 p.
// GEMM: thread (tx,ty) = (tid&15, tid>>4) owns 2n x 4p; A read as float2 (b64).
// Epilogue: 256 threads, 8 lanes per node x 16 p each, shfl_xor width-8 reduce.
// Per-p 32-bit stripe word reassembled from the 4 bitplanes.
// ---------------------------------------------------------------------------
__global__ __launch_bounds__(512) void attn_kernel(const float* __restrict__ emb,
                                                   const float* __restrict__ projT,
                                                   const unsigned long long* __restrict__ msk,
                                                   const int* __restrict__ pos_idx,
                                                   const float* __restrict__ pe2,
                                                   const float* __restrict__ w_weight,
                                                   const float* __restrict__ dinv,
                                                   float* __restrict__ v) {
    __shared__ float At[32][36];        // At[dk][nn] = emb[n0+nn][d0+dk], +4 pad
    __shared__ float B[32][128];        // B[dk][p]   = projT[d0+dk][p]
    __shared__ float S[32][129];        // masked scores, padded
    __shared__ unsigned int mword[P];   // 32-col stripe mask word per p
    __shared__ int   posrow[P];
    __shared__ float pe2s[P];
    __shared__ float fac[P];            // deduped dinv[pos[p]]
    __shared__ float w1[D];

    int tid = threadIdx.x;
    int tx = tid & 15;    // n-group: n = n0 + tx*2 + i
    int ty = tid >> 4;    // p-group: p = ty*4 + j
    int n0 = blockIdx.x * 32;

    if (tid < P) {
        int r0 = pos_idx[tid];
        posrow[tid] = r0;
        pe2s[tid] = pe2[tid];
        float f = dinv[r0];
        if (tid > 0 && pos_idx[tid - 1] == r0) f = 0.f;  // dedupe (sorted idx)
        fac[tid] = f;
    }
    if (tid < D) w1[tid] = w_weight[tid];

    float acc[2][4];
    #pragma unroll
    for (int i = 0; i < 2; i++)
        #pragma unroll
        for (int j = 0; j < 4; j++) acc[i][j] = 0.f;

    for (int d0 = 0; d0 < D; d0 += 32) {
        __syncthreads();   // covers init stores on first iter, tile reuse after
        if (tid < 256) {   // stage A chunk transposed: 1024 floats
            int nn = tid >> 3;
            int dk0 = (tid & 7) * 4;
            float4 v0 = *(const float4*)(emb + (size_t)(n0 + nn) * D + d0 + dk0);
            At[dk0 + 0][nn] = v0.x; At[dk0 + 1][nn] = v0.y;
            At[dk0 + 2][nn] = v0.z; At[dk0 + 3][nn] = v0.w;
        }
        #pragma unroll
        for (int r = 0; r < 2; r++) {   // stage B chunk: 4096 floats
            int f = (r * 512 + tid) * 4;
            int dk = f >> 7, pp = f & 127;
            *(float4*)&B[dk][pp] = *(const float4*)(projT + (size_t)(d0 + dk) * P + pp);
        }
        __syncthreads();
        #pragma unroll
        for (int dk = 0; dk < 32; dk++) {
            float2 a2 = *(const float2*)&At[dk][tx * 2];   // one b64 read
            float4 b4 = *(const float4*)&B[dk][ty * 4];
            acc[0][0] += a2.x * b4.x; acc[0][1] += a2.x * b4.y;
            acc[0][2] += a2.x * b4.z; acc[0][3] += a2.x * b4.w;
            acc[1][0] += a2.y * b4.x; acc[1][1] += a2.y * b4.y;
            acc[1][2] += a2.y * b4.z; acc[1][3] += a2.y * b4.w;
        }
    }

    // reassemble the 32-column stripe word from 4 bitplanes:
    // bit nn (= 4i+c) of mword[p] = bit i of byte (plane c >> sh)
    if (tid < P) {
        size_t base = (size_t)posrow[tid] * MW;
        int q  = n0 >> 8;               // plane word index
        int sh = (n0 >> 2) & 63;        // bit offset of this stripe's 8 float4
        unsigned int b0 = (unsigned int)((msk[base +      q] >> sh) & 0xFFu);
        unsigned int b1 = (unsigned int)((msk[base + 32 + q] >> sh) & 0xFFu);
        unsigned int b2 = (unsigned int)((msk[base + 64 + q] >> sh) & 0xFFu);
        unsigned int b3 = (unsigned int)((msk[base + 96 + q] >> sh) & 0xFFu);
        mword[tid] = spread4(b0) | (spread4(b1) << 1) | (spread4(b2) << 2) | (spread4(b3) << 3);
    }
    __syncthreads();

    // mask + write scores
    #pragma unroll
    for (int j = 0; j < 4; j++) {
        int p = ty * 4 + j;
        unsigned int w = mword[p];
        #pragma unroll
        for (int i = 0; i < 2; i++) {
            int nn = tx * 2 + i;
            S[nn][p] = ((w >> nn) & 1u) ? acc[i][j] : 0.f;
        }
    }
    __syncthreads();

    // parallel epilogue: 8 lanes per node, 16 p each.
    // softmax over p + context-fold + e1 + hop-1 + sigmoid + v write
    if (tid < 256) {
        int g = tid >> 3;        // node 0..31
        int l = tid & 7;         // p-chunk 0..7 (consecutive tids -> same wave)
        int n = n0 + g;
        // e1 partial: d = l*32 .. l*32+31 (emb row is L1/L2-hot from GEMM)
        float e1 = 0.f;
        const float* erow = emb + (size_t)n * D + l * 32;
        #pragma unroll 8
        for (int d = 0; d < 32; d++) e1 += erow[d] * w1[l * 32 + d];
        float mm = -1e30f;
        #pragma unroll
        for (int t = 0; t < 16; t++) mm = fmaxf(mm, S[g][l * 16 + t]);
        #pragma unroll
        for (int off = 1; off < 8; off <<= 1) mm = fmaxf(mm, __shfl_xor(mm, off, 8));
        float Z = 0.f, ape = 0.f, vs = 0.f;
        #pragma unroll
        for (int t = 0; t < 16; t++) {
            int p = l * 16 + t;
            float ex = __expf(S[g][p] - mm);
            Z += ex;
            ape += ex * pe2s[p];
            if ((mword[p] >> g) & 1u) vs += fac[p];
        }
        #pragma unroll
        for (int off = 1; off < 8; off <<= 1) {
            Z   += __shfl_xor(Z, off, 8);
            ape += __shfl_xor(ape, off, 8);
            vs  += __shfl_xor(vs, off, 8);
            e1  += __shfl_xor(e1, off, 8);
        }
        if (l == 0) {
            float logit = e1 + ape / Z;
            float mw = 1.f / (1.f + __expf(-logit));
            v[n] = vs * dinv[n] * mw;
        }
    }
}

// ---------------------------------------------------------------------------
// K3: out[j] = w_final * dinv[j] * sum_{n: bit(j,n)} v[n]   (adj symmetric)
// One wave per row (4 rows/block); iterate set bits of the 4 bitplanes.
// word wi: plane c = wi>>5, q = wi&31; bit k -> column q*256 + 4k + c.
// ---------------------------------------------------------------------------
__global__ __launch_bounds__(256) void final_kernel(const unsigned long long* __restrict__ msk,
                                                    const float* __restrict__ vvec,
                                                    const float* __restrict__ dinv,
                                                    const float* __restrict__ w_final,
                                                    float* __restrict__ out) {
    int wave = threadIdx.x >> 6, lane = threadIdx.x & 63;
    int row = blockIdx.x * 4 + wave;
    const unsigned long long* mrow = msk + (size_t)row * MW;
    float s = 0.f;
    #pragma unroll
    for (int t = 0; t < 2; t++) {
        int wi = t * 64 + lane;
        unsigned long long m = mrow[wi];
        int c = wi >> 5;
        int q = wi & 31;
        int base = q * 256 + c;
        while (m) {
            int k = __builtin_ctzll(m);
            s += vvec[base + 4 * k];
            m &= m - 1;
        }
    }
    for (int off = 32; off > 0; off >>= 1) s += __shfl_down(s, off, 64);
    if (lane == 0) out[row] = s * dinv[row] * w_final[0];
}

// ---------------------------------------------------------------------------
extern "C" void kernel_launch(void* const* d_in, const int* in_sizes, int n_in,
                              void* d_out, int out_size, void* d_ws, size_t ws_size,
                              hipStream_t stream) {
    const float* adj    = (const float*)d_in[0];
    const float* emb    = (const float*)d_in[1];
    const float* w_att  = (const float*)d_in[2];
    const float* b_att  = (const float*)d_in[3];
    const float* w_w    = (const float*)d_in[4];
    const float* w_f    = (const float*)d_in[5];
    const int*   pos    = (const int*)d_in[6];
    float* out = (float*)d_out;

    float* ws     = (float*)d_ws;
    float* dinv   = ws;                       // N
    float* projT  = dinv + N;                 // D*P
    float* pe2    = projT + (size_t)D * P;    // P
    float* v      = pe2 + P;                  // N
    // byte offset of msk = (N + D*P + P + N)*4 = 195584, 8B-aligned
    unsigned long long* msk = (unsigned long long*)(v + N);  // 8000*128 ull = 8.19 MB

    prep_kernel <<<N + P,  256, 0, stream>>>(adj, emb, w_att, b_att, w_w, pos,
                                             dinv, msk, projT, pe2);
    attn_kernel <<<N / 32, 512, 0, stream>>>(emb, projT, msk, pos, pe2, w_w, dinv, v);
    final_kernel<<<N / 4,  256, 0, stream>>>(msk, v, dinv, w_f, out);
}